// Round 9
// baseline (187.138 us; speedup 1.0000x reference)
//
#include <hip/hip_runtime.h>

// PWC-Net correlation (md=4, 81 disps) + leaky_relu(0.1), mean over C=256.
// B=8 C=256 H=96 W=128, f32 in/out.
//
// R9 = R7 (best, 126us) + double-buffered LDS with ONE barrier per chunk.
// Block = 3 waves (192 thr), wave = one dy of 3-dy group; grid =
// 8(batch==XCD) x 48(h-tiles) x 3(dy-groups) = 1152 blocks.
// Per chunk: STAGE(cc+1 -> buf^1) issued BEFORE COMPUTE(buf), single
// __syncthreads() -- global-load latency hides under compute, barriers
// halve (64 -> 33). Both x1 and x2 staged via LDS (R8 lesson: x1 direct
// global->reg loads thrash L1 across co-resident blocks, FETCH 2.5x,
// 227us). Staging keeps per-task load->pack->write live ranges short
// (R7-proven 56 VGPR; R5/R6 lesson: compiler pins ~84-92 VGPR, spills
// are fatal; sentinel = WRITE_SIZE >> 31MB).
// f16-pair packing, v_dot2_f32_f16, conflict-free XOR swizzle for b128.

#define B_ 8
#define C_ 256
#define H_ 96
#define W_ 128
#define TH 2
#define CC 8
#define NCH (C_ / CC)            // 32 chunks
#define HW (H_ * W_)
#define CHSTRIDE (CC * HW)       // floats, fits u32
#define S2SZ (4 * 544)           // 2176 u32 (4 staged x2 rows)
#define S1SZ (TH * 512)          // 1024 u32
#define SMSZ (S2SZ + S1SZ)       // 3200 u32 = 12.8 KB per buffer
#define NTHR 192
#define NTASK 800                // 256 x1 + 544 x2 float4-pair tasks
#define NR 5                     // staging rounds: 192*5 >= 800

typedef __fp16 h2_t __attribute__((ext_vector_type(2)));
union H2U { unsigned int u; h2_t h; };

__device__ __forceinline__ h2_t u_as_h2(unsigned int u) { H2U x; x.u = u; return x.h; }

__device__ __forceinline__ unsigned int packh2(float a, float b) {
    H2U x; x.h = __builtin_amdgcn_cvt_pkrtz(a, b); return x.u;
}

#if __has_builtin(__builtin_amdgcn_fdot2)
__device__ __forceinline__ float dot2(unsigned int a, unsigned int b, float c) {
    return __builtin_amdgcn_fdot2(u_as_h2(a), u_as_h2(b), c, false);
}
#else
__device__ __forceinline__ float dot2(unsigned int a, unsigned int b, float c) {
    h2_t ha = u_as_h2(a), hb = u_as_h2(b);
    return c + (float)ha[0] * (float)hb[0] + (float)ha[1] * (float)hb[1];
}
#endif

__global__ __attribute__((amdgpu_flat_work_group_size(NTHR, NTHR)))
void corr_kernel(const float* __restrict__ x1, const float* __restrict__ x2,
                 float* __restrict__ out)
{
    // per buffer: s2 (4 rows x 544) at [0, S2SZ), s1 (2 rows x 512) after
    __shared__ __align__(16) unsigned int smem[2][SMSZ];   // 25.6 KB

    const int b   = blockIdx.x;       // batch == XCD (x fastest => round-robin)
    const int h0  = blockIdx.y * TH;
    const int dg  = blockIdx.z;       // dy = 3*dg + wid
    const int tid = threadIdx.x;
    const int wid = tid >> 6;         // 0..2
    const int lane = tid & 63;
    const int hr  = lane >> 5;        // 0..1
    const int wq  = lane & 31;        // 32 groups of 4 w pixels

    // ---------------- staging descriptors (5 rounds x 192 threads) ---------
    // task u<256: x1. cp=u&3, w4=(u>>2)&31, rx=u>>7.
    // task 256<=u<800: x2. v=u-256: cp=v&3, q=v>>2, g=q%34 (0..33), r=q/34.
    // LDS slot for pixel-slot s, ch-pair cp, row r:
    //   r*544(or 512) + (s>>3)*32 + (((s&7)^((s>>3)&7)^(r&7))<<2) + cp
    // task covers s=4g..4g+3 -> idx_k = c + ((k^X)<<2).
    unsigned off_[NR];
    int cx_[NR];                       // c | (X<<16)
    int mval = 0, msrc = 0;            // valid / source-is-x2 bitmasks
    #pragma unroll
    for (int r5 = 0; r5 < NR; ++r5) {
        const int u = tid + NTHR * r5;
        unsigned off = 0; int c = 0, X = 0; bool val = false, src2 = false;
        if (u < 256) {
            const int cp = u & 3, w4 = (u >> 2) & 31, rx = u >> 7;
            off = ((unsigned)(b * C_ + 2 * cp) * H_ + (unsigned)(h0 + rx)) * W_
                + (unsigned)(4 * w4);
            c = S2SZ + rx * 512 + (w4 >> 1) * 32 + cp;
            X = (4 * (w4 & 1)) ^ ((w4 >> 1) & 7) ^ rx;
            val = true;
        } else if (u < NTASK) {
            const int v = u - 256;
            const int cp = v & 3, q = v >> 2;
            const int g = q % 34, r = q / 34;
            const int h2 = h0 + 3 * dg + r - 4;
            val = (h2 >= 0) && (h2 < H_) && (g >= 1) && (g <= 32);
            const int h2c = val ? h2 : 0, gc = val ? g : 1;
            off = ((unsigned)(b * C_ + 2 * cp) * H_ + (unsigned)h2c) * W_
                + (unsigned)(4 * gc - 4);
            c = r * 544 + (g >> 1) * 32 + cp;
            X = (4 * (g & 1)) ^ ((g >> 1) & 7) ^ (r & 7);
            src2 = true;
        }
        off_[r5] = off;
        cx_[r5]  = c | (X << 16);
        mval |= (int)val << r5;
        msrc |= (int)src2 << r5;
    }

    auto STAGE = [&](int cc, unsigned int* SM) {
        const unsigned co = (unsigned)cc * (unsigned)CHSTRIDE;
        #pragma unroll
        for (int r5 = 0; r5 < NR; ++r5) {
            if ((mval >> r5) & 1) {
                const float* base = ((msrc >> r5) & 1) ? x2 : x1;
                const float4 A  = *reinterpret_cast<const float4*>(base + off_[r5] + co);
                const float4 Bv = *reinterpret_cast<const float4*>(base + off_[r5] + co + HW);
                const int c = cx_[r5] & 0xffff;
                const int X = cx_[r5] >> 16;
                SM[c + ((0 ^ X) << 2)] = packh2(A.x, Bv.x);
                SM[c + ((1 ^ X) << 2)] = packh2(A.y, Bv.y);
                SM[c + ((2 ^ X) << 2)] = packh2(A.z, Bv.z);
                SM[c + ((3 ^ X) << 2)] = packh2(A.w, Bv.w);
            }
        }
    };

    // ---------------- compute setup ----------------
    const int base1 = S2SZ + hr * 512 + (wq >> 1) * 32;
    const int S1X   = (4 * (wq & 1)) ^ ((wq >> 1) & 7) ^ hr;
    const int row   = hr + wid;            // staged x2 row 0..3

    int a2[12];                            // chunk-invariant x2 read addresses
    #pragma unroll
    for (int t = 0; t < 12; ++t) {
        const int sp = 4 * wq + t;         // padded pixel index 0..135
        a2[t] = row * 544 + (sp >> 3) * 32
              + (((sp & 7) ^ ((sp >> 3) & 7) ^ row) << 2);
    }

    float acc[4][9];
    #pragma unroll
    for (int p = 0; p < 4; ++p)
        #pragma unroll
        for (int d = 0; d < 9; ++d) acc[p][d] = 0.f;

    auto COMPUTE = [&](const unsigned int* SM) {
        uint4 x1v[4];
        #pragma unroll
        for (int p = 0; p < 4; ++p)
            x1v[p] = *reinterpret_cast<const uint4*>(&SM[base1 + ((p ^ S1X) << 2)]);
        #pragma unroll
        for (int t = 0; t < 12; ++t) {
            const uint4 x2v = *reinterpret_cast<const uint4*>(&SM[a2[t]]);
            #pragma unroll
            for (int p = 0; p < 4; ++p) {
                const int dxx = t - p;          // compile-time after unroll
                if (dxx >= 0 && dxx <= 8) {
                    float a = acc[p][dxx];
                    a = dot2(x1v[p].x, x2v.x, a);
                    a = dot2(x1v[p].y, x2v.y, a);
                    a = dot2(x1v[p].z, x2v.z, a);
                    a = dot2(x1v[p].w, x2v.w, a);
                    acc[p][dxx] = a;
                }
            }
        }
    };

    // ---------------- chunk loop: dbuf, ONE barrier per chunk --------------
    // zero pad slots of both buffers (never rewritten by STAGE)
    for (int i = tid; i < 2 * SMSZ; i += NTHR) (&smem[0][0])[i] = 0u;
    __syncthreads();                  // zeros visible before first STAGE
    STAGE(0, smem[0]);
    __syncthreads();                  // buf0 ready

    #pragma unroll 1
    for (int cc = 0; cc < NCH; cc += 2) {
        STAGE(cc + 1, smem[1]);       // loads issued before compute
        COMPUTE(smem[0]);
        __syncthreads();              // buf1 ready / buf0 free
        if (cc + 2 < NCH) STAGE(cc + 2, smem[0]);
        COMPUTE(smem[1]);
        __syncthreads();              // buf0 ready / buf1 free
    }

    // ---------------- epilogue: mean + leaky_relu + coalesced f32x4 writes -
    const float inv = 1.0f / 256.0f;
    const int dy = 3 * dg + wid;
    float* ob = out + (((size_t)(b * 81 + dy * 9)) * H_ + (h0 + hr)) * W_ + wq * 4;
    #pragma unroll
    for (int dxx = 0; dxx < 9; ++dxx) {
        float4 o;
        float v;
        v = acc[0][dxx] * inv; o.x = v >= 0.f ? v : 0.1f * v;
        v = acc[1][dxx] * inv; o.y = v >= 0.f ? v : 0.1f * v;
        v = acc[2][dxx] * inv; o.z = v >= 0.f ? v : 0.1f * v;
        v = acc[3][dxx] * inv; o.w = v >= 0.f ? v : 0.1f * v;
        *reinterpret_cast<float4*>(ob + (size_t)dxx * HW) = o;
    }
}

extern "C" void kernel_launch(void* const* d_in, const int* in_sizes, int n_in,
                              void* d_out, int out_size, void* d_ws, size_t ws_size,
                              hipStream_t stream) {
    const float* x1 = (const float*)d_in[0];
    const float* x2 = (const float*)d_in[1];
    float* out = (float*)d_out;
    corr_kernel<<<dim3(B_, H_ / TH, 3), dim3(NTHR), 0, stream>>>(x1, x2, out);
}

// Round 10
// 173.805 us; speedup vs baseline: 1.0767x; 1.0767x over previous
//
#include <hip/hip_runtime.h>

// PWC-Net correlation (md=4, 81 disps) + leaky_relu(0.1), mean over C=256.
// B=8 C=256 H=96 W=128, f32 in/out.
//
// R10 = R7 (best, 126us) with TWO chunks staged per phase:
//   STAGE(cc & cc+1 -> buf0/buf1); sync; COMPUTE(buf0); COMPUTE(buf1); sync
// Barriers 66 -> 33, one vmcnt drain per TWO chunks (the per-chunk
// load-latency drain + barrier convoy was the unexplained ~60us in R7).
// Index math / swizzle / task mapping / compute are R7's verbatim.
// Block = 3 waves (192 thr), wave = one dy of 3-dy group; grid =
// 8(batch==XCD) x 48(h-tiles) x 3(dy-groups) = 1152 blocks.
// Lessons: R5/R6 compiler pins ~84 VGPR, spills fatal (sentinel:
// WRITE_SIZE >> 31MB); R8 x1 must stay LDS-shared; R9 stage-before-
// compute without vmcnt split doesn't overlap (packs drain immediately).

#define B_ 8
#define C_ 256
#define H_ 96
#define W_ 128
#define TH 2
#define CC 8
#define NCH (C_ / CC)            // 32 chunks
#define HW (H_ * W_)
#define CHSTRIDE (CC * HW)       // floats, fits u32
#define S2SZ (4 * 544)           // 2176 u32 (4 staged x2 rows)
#define S1SZ (TH * 512)          // 1024 u32
#define SMSZ (S2SZ + S1SZ)       // 3200 u32 = 12.8 KB per buffer
#define NTHR 192
#define NTASK1 800               // per-chunk tasks: 256 x1 + 544 x2
#define NTASK2 1600              // two chunks per phase
#define NR2 9                    // staging rounds: 192*9 >= 1600

typedef __fp16 h2_t __attribute__((ext_vector_type(2)));
union H2U { unsigned int u; h2_t h; };

__device__ __forceinline__ h2_t u_as_h2(unsigned int u) { H2U x; x.u = u; return x.h; }

__device__ __forceinline__ unsigned int packh2(float a, float b) {
    H2U x; x.h = __builtin_amdgcn_cvt_pkrtz(a, b); return x.u;
}

#if __has_builtin(__builtin_amdgcn_fdot2)
__device__ __forceinline__ float dot2(unsigned int a, unsigned int b, float c) {
    return __builtin_amdgcn_fdot2(u_as_h2(a), u_as_h2(b), c, false);
}
#else
__device__ __forceinline__ float dot2(unsigned int a, unsigned int b, float c) {
    h2_t ha = u_as_h2(a), hb = u_as_h2(b);
    return c + (float)ha[0] * (float)hb[0] + (float)ha[1] * (float)hb[1];
}
#endif

__global__ __attribute__((amdgpu_flat_work_group_size(NTHR, NTHR)))
void corr_kernel(const float* __restrict__ x1, const float* __restrict__ x2,
                 float* __restrict__ out)
{
    // per buffer: s2 (4 rows x 544) at [0, S2SZ), s1 (2 rows x 512) after
    __shared__ __align__(16) unsigned int smem[2][SMSZ];   // 25.6 KB

    const int b   = blockIdx.x;       // batch == XCD (x fastest => round-robin)
    const int h0  = blockIdx.y * TH;
    const int dg  = blockIdx.z;       // dy = 3*dg + wid
    const int tid = threadIdx.x;
    const int wid = tid >> 6;         // 0..2
    const int lane = tid & 63;
    const int hr  = lane >> 5;        // 0..1
    const int wq  = lane & 31;        // 32 groups of 4 w pixels

    // ---------------- staging descriptors (9 rounds x 192 threads) ---------
    // phase task u in [0,1600): j = chunk parity (u>=800), v = u - 800*j.
    // v<256: x1. cp=v&3, w4=(v>>2)&31, rx=v>>7.
    // 256<=v<800: x2. t=v-256: cp=t&3, q=t>>2, g=q%34 (0..33), r=q/34 (0..3).
    // LDS slot (buffer j folded into c as j*SMSZ):
    //   j*SMSZ + [S2SZ +] r*544(512) + (s>>3)*32 + (((s&7)^((s>>3)&7)^(r&7))<<2) + cp
    // task covers s=4g..4g+3 -> idx_k = c + ((k^X)<<2).
    unsigned off_[NR2];
    int cx_[NR2];                      // c | (X<<16)
    int mval = 0, msrc = 0, mbuf = 0;  // valid / source-is-x2 / chunk-parity
    #pragma unroll
    for (int r9 = 0; r9 < NR2; ++r9) {
        const int u = tid + NTHR * r9;
        const int j = (u >= NTASK1) ? 1 : 0;
        const int v = u - NTASK1 * j;
        const bool act = (u < NTASK2);
        unsigned off = 0; int c = 0, X = 0; bool val = false, src2 = false;
        if (v < 256) {
            const int cp = v & 3, w4 = (v >> 2) & 31, rx = v >> 7;
            off = ((unsigned)(b * C_ + 2 * cp) * H_ + (unsigned)(h0 + rx)) * W_
                + (unsigned)(4 * w4);
            c = j * SMSZ + S2SZ + rx * 512 + (w4 >> 1) * 32 + cp;
            X = (4 * (w4 & 1)) ^ ((w4 >> 1) & 7) ^ rx;
            val = act;
        } else {
            const int t = v - 256;
            const int cp = t & 3, q = t >> 2;
            const int g = q % 34, r = q / 34;
            const int h2 = h0 + 3 * dg + r - 4;
            val = act && (h2 >= 0) && (h2 < H_) && (g >= 1) && (g <= 32);
            const int h2c = val ? h2 : 0, gc = val ? g : 1;
            off = ((unsigned)(b * C_ + 2 * cp) * H_ + (unsigned)h2c) * W_
                + (unsigned)(4 * gc - 4);
            c = j * SMSZ + r * 544 + (g >> 1) * 32 + cp;
            X = (4 * (g & 1)) ^ ((g >> 1) & 7) ^ (r & 7);
            src2 = true;
        }
        off_[r9] = off;
        cx_[r9]  = c | (X << 16);
        mval |= (int)val << r9;
        msrc |= (int)src2 << r9;
        mbuf |= j << r9;
    }

    auto STAGE = [&](int cc) {
        unsigned int* SM = &smem[0][0];
        #pragma unroll
        for (int r9 = 0; r9 < NR2; ++r9) {
            if ((mval >> r9) & 1) {
                const float* base = ((msrc >> r9) & 1) ? x2 : x1;
                const unsigned co =
                    (unsigned)(cc + ((mbuf >> r9) & 1)) * (unsigned)CHSTRIDE;
                const float4 A  = *reinterpret_cast<const float4*>(base + off_[r9] + co);
                const float4 Bv = *reinterpret_cast<const float4*>(base + off_[r9] + co + HW);
                const int c = cx_[r9] & 0xffff;
                const int X = cx_[r9] >> 16;
                SM[c + ((0 ^ X) << 2)] = packh2(A.x, Bv.x);
                SM[c + ((1 ^ X) << 2)] = packh2(A.y, Bv.y);
                SM[c + ((2 ^ X) << 2)] = packh2(A.z, Bv.z);
                SM[c + ((3 ^ X) << 2)] = packh2(A.w, Bv.w);
            }
        }
    };

    // ---------------- compute setup (R7 verbatim) ----------------
    const int base1 = S2SZ + hr * 512 + (wq >> 1) * 32;
    const int S1X   = (4 * (wq & 1)) ^ ((wq >> 1) & 7) ^ hr;
    const int row   = hr + wid;            // staged x2 row 0..3

    int a2[12];                            // chunk-invariant x2 read addresses
    #pragma unroll
    for (int t = 0; t < 12; ++t) {
        const int sp = 4 * wq + t;         // padded pixel index 0..135
        a2[t] = row * 544 + (sp >> 3) * 32
              + (((sp & 7) ^ ((sp >> 3) & 7) ^ row) << 2);
    }

    float acc[4][9];
    #pragma unroll
    for (int p = 0; p < 4; ++p)
        #pragma unroll
        for (int d = 0; d < 9; ++d) acc[p][d] = 0.f;

    auto COMPUTE = [&](const unsigned int* SM) {
        uint4 x1v[4];
        #pragma unroll
        for (int p = 0; p < 4; ++p)
            x1v[p] = *reinterpret_cast<const uint4*>(&SM[base1 + ((p ^ S1X) << 2)]);
        #pragma unroll
        for (int t = 0; t < 12; ++t) {
            const uint4 x2v = *reinterpret_cast<const uint4*>(&SM[a2[t]]);
            #pragma unroll
            for (int p = 0; p < 4; ++p) {
                const int dxx = t - p;          // compile-time after unroll
                if (dxx >= 0 && dxx <= 8) {
                    float a = acc[p][dxx];
                    a = dot2(x1v[p].x, x2v.x, a);
                    a = dot2(x1v[p].y, x2v.y, a);
                    a = dot2(x1v[p].z, x2v.z, a);
                    a = dot2(x1v[p].w, x2v.w, a);
                    acc[p][dxx] = a;
                }
            }
        }
    };

    // ---------------- chunk loop: 2 chunks per phase, 2 barriers/phase -----
    // zero pad slots of both buffers (never rewritten by STAGE)
    for (int i = tid; i < 2 * SMSZ; i += NTHR) (&smem[0][0])[i] = 0u;
    __syncthreads();                  // zeros visible before first STAGE

    #pragma unroll 1
    for (int cc = 0; cc < NCH; cc += 2) {
        STAGE(cc);                    // chunks cc -> buf0, cc+1 -> buf1
        __syncthreads();
        COMPUTE(&smem[0][0]);
        COMPUTE(&smem[1][0]);
        __syncthreads();
    }

    // ---------------- epilogue: mean + leaky_relu + coalesced f32x4 writes -
    const float inv = 1.0f / 256.0f;
    const int dy = 3 * dg + wid;
    float* ob = out + (((size_t)(b * 81 + dy * 9)) * H_ + (h0 + hr)) * W_ + wq * 4;
    #pragma unroll
    for (int dxx = 0; dxx < 9; ++dxx) {
        float4 o;
        float v;
        v = acc[0][dxx] * inv; o.x = v >= 0.f ? v : 0.1f * v;
        v = acc[1][dxx] * inv; o.y = v >= 0.f ? v : 0.1f * v;
        v = acc[2][dxx] * inv; o.z = v >= 0.f ? v : 0.1f * v;
        v = acc[3][dxx] * inv; o.w = v >= 0.f ? v : 0.1f * v;
        *reinterpret_cast<float4*>(ob + (size_t)dxx * HW) = o;
    }
}

extern "C" void kernel_launch(void* const* d_in, const int* in_sizes, int n_in,
                              void* d_out, int out_size, void* d_ws, size_t ws_size,
                              hipStream_t stream) {
    const float* x1 = (const float*)d_in[0];
    const float* x2 = (const float*)d_in[1];
    float* out = (float*)d_out;
    corr_kernel<<<dim3(B_, H_ / TH, 3), dim3(NTHR), 0, stream>>>(x1, x2, out);
}